// Round 11
// baseline (185.584 us; speedup 1.0000x reference)
//
#include <hip/hip_runtime.h>
#include <math.h>

// Problem constants (from reference)
#define DIMC   96
#define NHEADS 6
#define HD     16
#define WSZ    8
#define OWSZ   12
#define PADW   2
#define DD     24
#define LTOK   13824      // 24^3
#define NWIN   27         // 3^3
#define NKEY   1728       // 12^3
#define NROW   512        // 8^3
#define MLPH   192
#define PDIM   28         // 24 + 2*2
#define PD3    21952      // 28^3
#define TBL    6859       // 19^3
#define LSTR   82944      // 13824*6 (lbuf per-half stride)
#define AOSTR  1327104    // 13824*96 (ao per-half stride)
#define LOG2E  1.4426950408889634f

typedef __attribute__((ext_vector_type(4))) short bf16x4;
typedef __attribute__((ext_vector_type(8))) short bf16x8;
typedef __attribute__((ext_vector_type(4))) float f32x4;

// ---------------- helpers ----------------------------------------------------
__device__ __forceinline__ unsigned short bfround(float f) {
    unsigned u = __float_as_uint(f);
    return (unsigned short)((u + 0x7FFFu + ((u >> 16) & 1u)) >> 16);
}
__device__ __forceinline__ unsigned bfpack(float a, float b) {
    unsigned ua = __float_as_uint(a), ub = __float_as_uint(b);
    ua = (ua + 0x7FFFu + ((ua >> 16) & 1u)) >> 16;
    ub = (ub + 0x7FFFu + ((ub >> 16) & 1u)) >> 16;
    return ua | (ub << 16);
}
__device__ __forceinline__ uint4 pack8(const float* v) {
    uint4 u;
    u.x = bfpack(v[0], v[1]); u.y = bfpack(v[2], v[3]);
    u.z = bfpack(v[4], v[5]); u.w = bfpack(v[6], v[7]);
    return u;
}
// fp32x4 -> bf16x4 by truncation (P values; <0.4% rel bias; l uses same P)
__device__ __forceinline__ bf16x4 pack4(f32x4 p) {
    union { uint2 u; bf16x4 v; } r;
    r.u.x = __builtin_amdgcn_perm(__float_as_uint(p[1]), __float_as_uint(p[0]), 0x07060302u);
    r.u.y = __builtin_amdgcn_perm(__float_as_uint(p[3]), __float_as_uint(p[2]), 0x07060302u);
    return r.v;
}
__device__ __forceinline__ f32x4 mfma16(bf16x4 a, bf16x4 b, f32x4 c) {
#if __has_builtin(__builtin_amdgcn_mfma_f32_16x16x16bf16_1k)
    return __builtin_amdgcn_mfma_f32_16x16x16bf16_1k(a, b, c, 0, 0, 0);
#else
    bf16x8 a8 = {a[0], a[1], a[2], a[3], 0, 0, 0, 0};
    bf16x8 b8 = {b[0], b[1], b[2], b[3], 0, 0, 0, 0};
    return __builtin_amdgcn_mfma_f32_16x16x32_bf16(a8, b8, c, 0, 0, 0);
#endif
}
__device__ __forceinline__ float fexp2(float x) {
#if __has_builtin(__builtin_amdgcn_exp2f)
    return __builtin_amdgcn_exp2f(x);
#else
    return exp2f(x);
#endif
}

// ---------------- kernel 1: qkv GEMM + pad-border zero + MLP weight pack -----
#define QKVB 1296
#define ZB   515     // ceil(21952*6/256)
#define WPB  45      // 5760 uint4 / 256 (rounded up)
__global__ __launch_bounds__(256) void qkvz_kernel(
        const float* __restrict__ X, const float* __restrict__ W,
        const float* __restrict__ bias, const float* __restrict__ lnw,
        const float* __restrict__ lnb,
        const float* __restrict__ projw, const float* __restrict__ fc1w,
        const float* __restrict__ fc2w,
        unsigned short* __restrict__ q16, unsigned short* __restrict__ kvp2,
        uint4* __restrict__ wpack) {
    __shared__ uint4 Af4[2 * 3 * 4 * 16];   // 6 KB
    __shared__ uint4 Bf4[6 * 3 * 4 * 16];   // 18 KB
    int bx = blockIdx.x, tid = threadIdx.x;

    if (bx >= QKVB + ZB) {   // ---- weight pack ----
        int u = (bx - QKVB - ZB) * 256 + tid;
        if (u < 5760) {
            int p = (u < 1152) ? u : (u < 3456 ? (u - 1152) % 1152 : (u - 3456) % 1152);
            int nn = p & 15, r = p >> 4, qg = r & 3, r2 = r >> 2;
            int kt = r2 % 3, ct = r2 / 3;
            int n = ct * 16 + nn, g = kt * 4 + qg;
            const float* src;
            if (u < 1152)      src = projw + n * 96 + g * 8;
            else if (u < 3456) { int nc = (u - 1152) / 1152; src = fc1w + (long)(nc * 96 + n) * 96 + g * 8; }
            else               { int kh = (u - 3456) / 1152; src = fc2w + (long)n * 192 + kh * 96 + g * 8; }
            const float4* s4 = (const float4*)src;
            float v[8];
            float4 t0 = s4[0], t1 = s4[1];
            v[0]=t0.x; v[1]=t0.y; v[2]=t0.z; v[3]=t0.w;
            v[4]=t1.x; v[5]=t1.y; v[6]=t1.z; v[7]=t1.w;
            wpack[u] = pack8(v);
        }
        return;
    }
    if (bx >= QKVB) {        // ---- pad-border zero ----
        int t = (bx - QKVB) * 256 + tid;
        if (t < 21952 * 6) {
            int head = t / PD3, pos = t % PD3;
            int d = pos / 784, h = (pos / 28) % 28, w = pos % 28;
            if (d < 2 || d >= 26 || h < 2 || h >= 26 || w < 2 || w >= 26) {
                uint4* p = (uint4*)(kvp2 + ((long)head * PD3 + pos) * 32);
                uint4 z = make_uint4(0, 0, 0, 0);
                p[0] = z; p[1] = z; p[2] = z; p[3] = z;
            }
        }
        return;
    }

    // ---- qkv GEMM sub-block ----
    int nc   = bx % 3;
    int row0 = (bx / 3) * 32;

    if (tid < 128) {   // stage A with LN1: 32 rows, 4 threads/row
        int row = tid >> 2, part = tid & 3;
        int rt = row >> 4, mm = row & 15;
        float v[24];
        const float4* xp = (const float4*)(X + (long)(row0 + row) * 96 + part * 24);
        float s = 0.f, sq = 0.f;
        #pragma unroll
        for (int i = 0; i < 6; ++i) {
            float4 t = xp[i];
            v[i*4+0] = t.x; v[i*4+1] = t.y; v[i*4+2] = t.z; v[i*4+3] = t.w;
            s  += t.x + t.y + t.z + t.w;
            sq += t.x*t.x + t.y*t.y + t.z*t.z + t.w*t.w;
        }
        s  += __shfl_xor(s, 1);  s  += __shfl_xor(s, 2);
        sq += __shfl_xor(sq, 1); sq += __shfl_xor(sq, 2);
        float mean = s * (1.f / 96.f);
        float inv  = rsqrtf(sq * (1.f / 96.f) - mean * mean + 1e-5f);
        const float4* wp = (const float4*)(lnw + part * 24);
        const float4* bp = (const float4*)(lnb + part * 24);
        #pragma unroll
        for (int i = 0; i < 6; ++i) {
            float4 wv = wp[i], bv = bp[i];
            v[i*4+0] = (v[i*4+0] - mean) * inv * wv.x + bv.x;
            v[i*4+1] = (v[i*4+1] - mean) * inv * wv.y + bv.y;
            v[i*4+2] = (v[i*4+2] - mean) * inv * wv.z + bv.z;
            v[i*4+3] = (v[i*4+3] - mean) * inv * wv.w + bv.w;
        }
        #pragma unroll
        for (int gg = 0; gg < 3; ++gg) {
            int g = part * 3 + gg;
            int kt = g >> 2, qq = g & 3;
            Af4[((rt * 3 + kt) * 4 + qq) * 16 + mm] = pack8(v + gg * 8);
        }
    }
    for (int idx = tid; idx < 96 * 12; idx += 256) {
        int n = idx / 12;
        int g = idx % 12;
        const float4* wp = (const float4*)(W + (long)(nc * 96 + n) * 96 + g * 8);
        float v[8];
        float4 t0 = wp[0], t1 = wp[1];
        v[0]=t0.x; v[1]=t0.y; v[2]=t0.z; v[3]=t0.w;
        v[4]=t1.x; v[5]=t1.y; v[6]=t1.z; v[7]=t1.w;
        int ct = n >> 4, nn = n & 15, kt = g >> 2, qg = g & 3;
        Bf4[((ct * 3 + kt) * 4 + qg) * 16 + nn] = pack8(v);
    }
    __syncthreads();

    int wave = tid >> 6, lane = tid & 63;
    int qq = lane >> 4, mI = lane & 15;
    int rt = wave & 1, cg = wave >> 1;

    f32x4 acc[3];
    #pragma unroll
    for (int j = 0; j < 3; ++j) acc[j] = (f32x4){0.f, 0.f, 0.f, 0.f};
    #pragma unroll
    for (int kt = 0; kt < 3; ++kt) {
        bf16x8 a = *(const bf16x8*)&Af4[((rt * 3 + kt) * 4 + qq) * 16 + mI];
        #pragma unroll
        for (int j = 0; j < 3; ++j) {
            bf16x8 b = *(const bf16x8*)&Bf4[(((cg * 3 + j) * 3 + kt) * 4 + qq) * 16 + mI];
            acc[j] = __builtin_amdgcn_mfma_f32_16x16x32_bf16(a, b, acc[j], 0, 0, 0);
        }
    }

    float bv[3];
    #pragma unroll
    for (int j = 0; j < 3; ++j) bv[j] = bias[nc * 96 + (cg * 3 + j) * 16 + mI];
    #pragma unroll
    for (int r = 0; r < 4; ++r) {
        int row = row0 + rt * 16 + qq * 4 + r;
        if (nc == 0) {
            unsigned short* op = q16 + (long)row * 96;
            // 0.25 (hd^-0.5) * log2(e): enables raw v_exp (2^x) in attention
            #pragma unroll
            for (int j = 0; j < 3; ++j)
                op[(cg * 3 + j) * 16 + mI] = bfround(0.25f * LOG2E * (acc[j][r] + bv[j]));
        } else {
            int d = row / 576, hh = (row / 24) % 24, w2 = row % 24;
            long pos = ((long)(d + 2) * 28 + (hh + 2)) * 28 + (w2 + 2);
            #pragma unroll
            for (int j = 0; j < 3; ++j) {
                int head = cg * 3 + j;
                kvp2[((long)head * PD3 + pos) * 32 +
                     (nc == 2 ? 16 : 0) + mI] = bfround(acc[j][r] + bv[j]);
            }
        }
    }
}

// ---------------- kernel 2: bias pack fp32 x log2e (MFMA C layout) -----------
__global__ __launch_bounds__(256) void bias_kernel(
        const int* __restrict__ rpi, const float* __restrict__ rpb,
        float* __restrict__ biasP) {
    int bx = blockIdx.x;                 // 1296 = head*216 + kt*2 + qh
    int head = bx / 216;
    int r2 = bx % 216;
    int kt = r2 >> 1, qh = r2 & 1;
    int k0 = kt * 16;
    int qi = qh * 256 + threadIdx.x;
    const int* rp = rpi + (long)qi * NKEY + k0;
    int idx[16];
    #pragma unroll
    for (int j = 0; j < 4; ++j) {
        int4 t = *(const int4*)(rp + j * 4);
        idx[j*4+0] = t.x; idx[j*4+1] = t.y; idx[j*4+2] = t.z; idx[j*4+3] = t.w;
    }
    #pragma unroll
    for (int quad = 0; quad < 4; ++quad) {
        float4 v;
        v.x = rpb[idx[quad*4+0] * NHEADS + head] * LOG2E;
        v.y = rpb[idx[quad*4+1] * NHEADS + head] * LOG2E;
        v.z = rpb[idx[quad*4+2] * NHEADS + head] * LOG2E;
        v.w = rpb[idx[quad*4+3] * NHEADS + head] * LOG2E;
        *(float4*)(biasP + ((((long)head*108 + kt)*4 + quad)*512 + qi)*4) = v;
    }
}

// ---------------- kernel 3: MFMA flash attention -----------------------------
// exp2-domain softmax; l on the MFMA pipe (all-ones A).
// XCD-affinity swizzle (fp32 bias this time — R7's swizzle test was confounded
// by the bf16 unpack): xcd=bid&7, L=xcd*162+slot pins each (head,half) group's
// 108 blocks (sharing a 1.8MB bias slice, 27x reuse) to one XCD's L2.
// Bias single-buffered: loads for chunk c+1 issued straight into bcur after
// the S-MFMAs consume it (no bnxt copy -> -32 v_mov/chunk, -32 VGPR).
#define KSTR 20
#define VSTR 68
__global__ __launch_bounds__(256) void attn_kernel(
        const unsigned short* __restrict__ q, const unsigned short* __restrict__ kvp2,
        const float* __restrict__ biasP, float* __restrict__ ao,
        float* __restrict__ lbuf) {
    __shared__ unsigned short Ks[2][64 * KSTR];
    __shared__ unsigned short Vs[2][16 * VSTR];
    int bid = blockIdx.x;                 // 1296
    int xcd = bid & 7, slot = bid >> 3;
    int L = xcd * 162 + slot;
    int head = L / 216;
    int rem = L % 216;
    int half = rem / 108;
    int r3 = rem % 108;
    int quart = r3 / 27;
    int w = r3 % 27;
    int wd8 = (w / 9) * 8, wh8 = ((w / 3) % 3) * 8, ww8 = (w % 3) * 8;
    int tid = threadIdx.x, wave = tid >> 6, lane = tid & 63;
    int quad = lane >> 4, m16 = lane & 15;
    int key = tid >> 2, part = tid & 3;
    int c0 = half ? 13 : 0;
    int cn = half ? 14 : 13;

    auto kvaddr = [&](int c) -> const uint4* {
        int jg = c * 64 + key;
        int i = jg / 144, jh = (jg / 12) % 12, jw = jg % 12;
        long sp = ((long)(wd8 + i) * PDIM + (wh8 + jh)) * PDIM + (ww8 + jw);
        return (const uint4*)(kvp2 + ((long)head * PD3 + sp) * 32 + part * 8);
    };
    auto writeLDS = [&](int b, uint4 v) {
        if (part < 2) {
            *(uint2*)(&Ks[b][key * KSTR + part * 8])     = make_uint2(v.x, v.y);
            *(uint2*)(&Ks[b][key * KSTR + part * 8 + 4]) = make_uint2(v.z, v.w);
        } else {
            int d0 = (part - 2) * 8;
            Vs[b][(d0+0)*VSTR + key] = (unsigned short)(v.x);
            Vs[b][(d0+1)*VSTR + key] = (unsigned short)(v.x >> 16);
            Vs[b][(d0+2)*VSTR + key] = (unsigned short)(v.y);
            Vs[b][(d0+3)*VSTR + key] = (unsigned short)(v.y >> 16);
            Vs[b][(d0+4)*VSTR + key] = (unsigned short)(v.z);
            Vs[b][(d0+5)*VSTR + key] = (unsigned short)(v.z >> 16);
            Vs[b][(d0+6)*VSTR + key] = (unsigned short)(v.w);
            Vs[b][(d0+7)*VSTR + key] = (unsigned short)(v.w >> 16);
        }
    };

    int grow[2]; bf16x4 qf[2];
    #pragma unroll
    for (int qt = 0; qt < 2; ++qt) {
        int ql = quart * 128 + wave * 32 + qt * 16 + m16;
        int ld = ql >> 6, lh = (ql >> 3) & 7, lw = ql & 7;
        grow[qt] = ((wd8 + ld) * 24 + (wh8 + lh)) * 24 + (ww8 + lw);
        qf[qt] = *(const bf16x4*)(q + (long)grow[qt] * 96 + head * 16 + quad * 4);
    }

    const float* bbase = biasP + (long)head * 884736 + quad * 2048
                         + ((quart * 128 + wave * 32 + m16) << 2);
    f32x4 bcur[2][4];
    #pragma unroll
    for (int qt = 0; qt < 2; ++qt)
        #pragma unroll
        for (int kt = 0; kt < 4; ++kt)
            bcur[qt][kt] = *(const f32x4*)(bbase + (long)(c0*4 + kt) * 8192 + qt * 64);

    writeLDS(0, *kvaddr(c0));

    const bf16x4 onesf = {(short)0x3F80, (short)0x3F80, (short)0x3F80, (short)0x3F80};
    f32x4 o[2], lacc[2];
    o[0] = (f32x4){0.f,0.f,0.f,0.f}; o[1] = (f32x4){0.f,0.f,0.f,0.f};
    lacc[0] = o[0]; lacc[1] = o[1];
    uint4 stgn;

    #pragma unroll 1
    for (int cc = 0; cc < cn; ++cc) {
        int c = c0 + cc;
        if (cc + 1 < cn) stgn = *kvaddr(c + 1);
        __syncthreads();
        int b = cc & 1;

        bf16x4 kf[4];
        #pragma unroll
        for (int kt = 0; kt < 4; ++kt)
            kf[kt] = *(const bf16x4*)(&Ks[b][(kt * 16 + m16) * KSTR + quad * 4]);

        f32x4 S[2][4];
        #pragma unroll
        for (int qt = 0; qt < 2; ++qt)
            #pragma unroll
            for (int kt = 0; kt < 4; ++kt)
                S[qt][kt] = mfma16(kf[kt], qf[qt], bcur[qt][kt]);

        // reload bias for next chunk straight into bcur (anti-dep after S)
        if (cc + 1 < cn) {
            const float* bp = bbase + (long)(c + 1) * 32768;
            #pragma unroll
            for (int qt = 0; qt < 2; ++qt)
                #pragma unroll
                for (int kt = 0; kt < 4; ++kt)
                    bcur[qt][kt] = *(const f32x4*)(bp + kt * 8192 + qt * 64);
        }

        bf16x4 Pb[2][4];
        #pragma unroll
        for (int qt = 0; qt < 2; ++qt)
            #pragma unroll
            for (int kt = 0; kt < 4; ++kt) {
                f32x4 p;
                #pragma unroll
                for (int r = 0; r < 4; ++r) p[r] = fexp2(S[qt][kt][r]);
                Pb[qt][kt] = pack4(p);
                lacc[qt] = mfma16(onesf, Pb[qt][kt], lacc[qt]);
            }

        #pragma unroll
        for (int kt = 0; kt < 4; ++kt) {
            bf16x4 vf = *(const bf16x4*)(&Vs[b][m16 * VSTR + kt * 16 + quad * 4]);
            o[0] = mfma16(vf, Pb[0][kt], o[0]);
            o[1] = mfma16(vf, Pb[1][kt], o[1]);
        }

        if (cc + 1 < cn) writeLDS((cc + 1) & 1, stgn);
    }

    float* aout = ao + (long)half * AOSTR;
    float* lout = lbuf + (long)half * LSTR;
    #pragma unroll
    for (int qt = 0; qt < 2; ++qt) {
        float4* op = (float4*)(aout + (long)grow[qt] * 96 + head * 16 + quad * 4);
        *op = make_float4(o[qt][0], o[qt][1], o[qt][2], o[qt][3]);
        if (quad == 0) lout[grow[qt] * 6 + head] = lacc[qt][0];
    }
}

// ---------------- kernel 4: fused MLP, 512 thr x 64 rows, weights resident ---
#define X2S 100
__global__ __launch_bounds__(512) void mlp_kernel(
        const float* __restrict__ ao0, const float* __restrict__ ao1,
        const float* __restrict__ lbuf, const uint4* __restrict__ wpack,
        const float* __restrict__ projb, const float* __restrict__ x,
        const float* __restrict__ ln2w, const float* __restrict__ ln2b,
        const float* __restrict__ fc1b, const float* __restrict__ fc2b,
        float* __restrict__ out) {
    __shared__ uint4 Ws[5760];               // 92160 B: proj | fc1(2) | fc2(2)
    __shared__ uint4 Af4[4 * 3 * 4 * 16];    // 12288 B
    __shared__ float x2s[64 * X2S];          // 25600 B
    __shared__ unsigned short h16[64 * 192]; // 24576 B  => 154624 B total
    int tid = threadIdx.x;
    int row0 = blockIdx.x * 64;
    int wave = tid >> 6, lane = tid & 63;
    int qq = lane >> 4, mI = lane & 15;
    int rt = wave & 3, cg = wave >> 2;       // 4 row tiles x 2 col groups

    for (int idx = tid; idx < 5760; idx += 512) Ws[idx] = wpack[idx];

    if (tid < 256) {
        int row = tid >> 2, part = tid & 3;
        int rtA = row >> 4, mm = row & 15;
        int grow = row0 + row;
        const float4* a0 = (const float4*)(ao0 + (long)grow * 96 + part * 24);
        const float4* a1 = (const float4*)(ao1 + (long)grow * 96 + part * 24);
        int ha = (part * 3) >> 1, hb = ha + 1;
        float inva = 1.f / (lbuf[grow*6 + ha] + lbuf[LSTR + grow*6 + ha]);
        float invb = 1.f / (lbuf[grow*6 + hb] + lbuf[LSTR + grow*6 + hb]);
        float v[24];
        #pragma unroll
        for (int i = 0; i < 6; ++i) {
            float4 u0 = a0[i], u1 = a1[i];
            #pragma unroll
            for (int j = 0; j < 4; ++j) {
                int gc = part * 24 + i * 4 + j;
                float lv = ((gc >> 4) == ha) ? inva : invb;
                float s = (j==0?u0.x+u1.x : j==1?u0.y+u1.y : j==2?u0.z+u1.z : u0.w+u1.w);
                v[i*4+j] = s * lv;
            }
        }
        #pragma unroll
        for (int gg = 0; gg < 3; ++gg) {
            int g = part * 3 + gg;
            int kt = g >> 2, q4 = g & 3;
            Af4[((rtA * 3 + kt) * 4 + q4) * 16 + mm] = pack8(v + gg * 8);
        }
    }
    __syncthreads();

    {
        f32x4 acc[3];
        #pragma unroll
        for (int j = 0; j < 3; ++j) acc[j] = (f32x4){0.f,0.f,0.f,0.f};
        #pragma unroll
        for (int kt = 0; kt < 3; ++kt) {
            bf16x8 a = *(const bf16x8*)&Af4[((rt * 3 + kt) * 4 + qq) * 16 + mI];
            #pragma unroll
            for (int j = 0; j < 3; ++j) {
                bf16x8 b = *(const bf16x8*)&Ws[(((cg * 3 + j) * 3 + kt) * 4 + qq) * 16 + mI];
                acc[j] = __builtin_amdgcn_mfma_f32_16x16x32_bf16(a, b, acc[j], 0, 0, 0);
            }
        }
        float bv[3];
        #pragma unroll
        for (int j = 0; j < 3; ++j) bv[j] = projb[(cg * 3 + j) * 16 + mI];
        #pragma unroll
        for (int r = 0; r < 4; ++r) {
            int row = rt * 16 + qq * 4 + r;
            int grow = row0 + row;
            #pragma unroll
            for (int j = 0; j < 3; ++j) {
                int col = (cg * 3 + j) * 16 + mI;
                x2s[row * X2S + col] = acc[j][r] + bv[j] + x[(long)grow * 96 + col];
            }
        }
    }
    __syncthreads();

    if (tid < 256) {
        int row = tid >> 2, part = tid & 3;
        int rtA = row >> 4, mm = row & 15;
        float v[24];
        const float4* xp = (const float4*)(x2s + row * X2S + part * 24);
        float s = 0.f, sq = 0.f;
        #pragma unroll
        for (int i = 0; i < 6; ++i) {
            float4 t = xp[i];
            v[i*4+0] = t.x; v[i*4+1] = t.y; v[i*4+2] = t.z; v[i*4+3] = t.w;
            s  += t.x + t.y + t.z + t.w;
            sq += t.x*t.x + t.y*t.y + t.z*t.z + t.w*t.w;
        }
        s  += __shfl_xor(s, 1);  s  += __shfl_xor(s, 2);
        sq += __shfl_xor(sq, 1); sq += __shfl_xor(sq, 2);
        float mean = s * (1.f / 96.f);
        float inv  = rsqrtf(sq * (1.f / 96.f) - mean * mean + 1e-5f);
        const float4* wp = (const float4*)(ln2w + part * 24);
        const float4* bp = (const float4*)(ln2b + part * 24);
        #pragma unroll
        for (int i = 0; i < 6; ++i) {
            float4 wv = wp[i], bv = bp[i];
            v[i*4+0] = (v[i*4+0] - mean) * inv * wv.x + bv.x;
            v[i*4+1] = (v[i*4+1] - mean) * inv * wv.y + bv.y;
            v[i*4+2] = (v[i*4+2] - mean) * inv * wv.z + bv.z;
            v[i*4+3] = (v[i*4+3] - mean) * inv * wv.w + bv.w;
        }
        #pragma unroll
        for (int gg = 0; gg < 3; ++gg) {
            int g = part * 3 + gg;
            int kt = g >> 2, q4 = g & 3;
            Af4[((rtA * 3 + kt) * 4 + q4) * 16 + mm] = pack8(v + gg * 8);
        }
    }
    __syncthreads();

    #pragma unroll
    for (int nc = 0; nc < 2; ++nc) {
        f32x4 acc[3];
        #pragma unroll
        for (int j = 0; j < 3; ++j) acc[j] = (f32x4){0.f,0.f,0.f,0.f};
        #pragma unroll
        for (int kt = 0; kt < 3; ++kt) {
            bf16x8 a = *(const bf16x8*)&Af4[((rt * 3 + kt) * 4 + qq) * 16 + mI];
            #pragma unroll
            for (int j = 0; j < 3; ++j) {
                bf16x8 b = *(const bf16x8*)&Ws[1152 + nc * 1152 +
                               (((cg * 3 + j) * 3 + kt) * 4 + qq) * 16 + mI];
                acc[j] = __builtin_amdgcn_mfma_f32_16x16x32_bf16(a, b, acc[j], 0, 0, 0);
            }
        }
        float bv[3];
        #pragma unroll
        for (int j = 0; j < 3; ++j) bv[j] = fc1b[nc * 96 + (cg * 3 + j) * 16 + mI];
        #pragma unroll
        for (int r = 0; r < 4; ++r) {
            int row = rt * 16 + qq * 4 + r;
            #pragma unroll
            for (int j = 0; j < 3; ++j) {
                int col = nc * 96 + (cg * 3 + j) * 16 + mI;
                float v = acc[j][r] + bv[j];
                float g = 0.5f * v * (1.f + erff(v * 0.70710678f));
                int fi = (((row >> 4) * 6 + (col >> 5)) * 4 + ((col >> 3) & 3)) * 16 + (row & 15);
                h16[fi * 8 + (col & 7)] = bfround(g);
            }
        }
    }
    __syncthreads();

    f32x4 acc2[3];
    #pragma unroll
    for (int j = 0; j < 3; ++j) acc2[j] = (f32x4){0.f,0.f,0.f,0.f};
    #pragma unroll
    for (int kh = 0; kh < 2; ++kh) {
        #pragma unroll
        for (int kt = 0; kt < 3; ++kt) {
            int ktA = kh * 3 + kt;
            bf16x8 a = *(const bf16x8*)&h16[(((rt * 6 + ktA) * 4 + qq) * 16 + mI) * 8];
            #pragma unroll
            for (int j = 0; j < 3; ++j) {
                bf16x8 b = *(const bf16x8*)&Ws[3456 + kh * 1152 +
                               (((cg * 3 + j) * 3 + kt) * 4 + qq) * 16 + mI];
                acc2[j] = __builtin_amdgcn_mfma_f32_16x16x32_bf16(a, b, acc2[j], 0, 0, 0);
            }
        }
    }
    float bv[3];
    #pragma unroll
    for (int j = 0; j < 3; ++j) bv[j] = fc2b[(cg * 3 + j) * 16 + mI];
    #pragma unroll
    for (int r = 0; r < 4; ++r) {
        int row = rt * 16 + qq * 4 + r;
        int grow = row0 + row;
        #pragma unroll
        for (int j = 0; j < 3; ++j) {
            int col = (cg * 3 + j) * 16 + mI;
            out[(long)grow * 96 + col] = acc2[j][r] + bv[j] + x2s[row * X2S + col];
        }
    }
}

// ---------------- launcher ---------------------------------------------------
extern "C" void kernel_launch(void* const* d_in, const int* in_sizes, int n_in,
                              void* d_out, int out_size, void* d_ws, size_t ws_size,
                              hipStream_t stream) {
    const float* x     = (const float*)d_in[0];
    const float* ln1w  = (const float*)d_in[1];
    const float* ln1b  = (const float*)d_in[2];
    const float* qkvw  = (const float*)d_in[3];
    const float* qkvb  = (const float*)d_in[4];
    const float* rpb   = (const float*)d_in[5];
    const float* projw = (const float*)d_in[6];
    const float* projb = (const float*)d_in[7];
    const float* ln2w  = (const float*)d_in[8];
    const float* ln2b  = (const float*)d_in[9];
    const float* fc1w  = (const float*)d_in[10];
    const float* fc1b  = (const float*)d_in[11];
    const float* fc2w  = (const float*)d_in[12];
    const float* fc2b  = (const float*)d_in[13];
    const int*   rpi   = (const int*)d_in[14];
    float* outp = (float*)d_out;

    float* ws = (float*)d_ws;
    float*          aop    = ws;                               // 2 x 1,327,104 f
    unsigned short* q16    = (unsigned short*)(ws + 2654208);  // 663,552 f
    unsigned short* kvp16  = (unsigned short*)(ws + 3317760);  // 2,107,392 f
    float*          biasPf = ws + 5425152;                     // 5,308,416 f (fp32)
    float*          lbuf   = ws + 10733568;                    // 165,888 f
    uint4*          wpack  = (uint4*)(ws + 10899456);          // 23,040 f (5760 u4)

    qkvz_kernel<<<QKVB + ZB + WPB, 256, 0, stream>>>(
        x, qkvw, qkvb, ln1w, ln1b, projw, fc1w, fc2w, q16, kvp16, wpack);
    bias_kernel<<<1296, 256, 0, stream>>>(rpi, rpb, biasPf);
    attn_kernel<<<NWIN * NHEADS * 4 * 2, 256, 0, stream>>>(q16, kvp16, biasPf, aop, lbuf);
    mlp_kernel<<<LTOK / 64, 512, 0, stream>>>(aop, aop + AOSTR, lbuf, wpack, projb, x,
                                              ln2w, ln2b, fc1b, fc2b, outp);
}

// Round 12
// 179.736 us; speedup vs baseline: 1.0325x; 1.0325x over previous
//
#include <hip/hip_runtime.h>
#include <math.h>

// Problem constants (from reference)
#define DIMC   96
#define NHEADS 6
#define HD     16
#define WSZ    8
#define OWSZ   12
#define PADW   2
#define DD     24
#define LTOK   13824      // 24^3
#define NWIN   27         // 3^3
#define NKEY   1728       // 12^3
#define NROW   512        // 8^3
#define MLPH   192
#define PDIM   28         // 24 + 2*2
#define PD3    21952      // 28^3
#define TBL    6859       // 19^3
#define LSTR   82944      // 13824*6 (lbuf per-half stride)
#define AOSTR  1327104    // 13824*96 (ao per-half stride)
#define LOG2E  1.4426950408889634f

typedef __attribute__((ext_vector_type(4))) short bf16x4;
typedef __attribute__((ext_vector_type(8))) short bf16x8;
typedef __attribute__((ext_vector_type(4))) float f32x4;

// ---------------- helpers ----------------------------------------------------
__device__ __forceinline__ unsigned short bfround(float f) {
    unsigned u = __float_as_uint(f);
    return (unsigned short)((u + 0x7FFFu + ((u >> 16) & 1u)) >> 16);
}
__device__ __forceinline__ unsigned bfpack(float a, float b) {
    unsigned ua = __float_as_uint(a), ub = __float_as_uint(b);
    ua = (ua + 0x7FFFu + ((ua >> 16) & 1u)) >> 16;
    ub = (ub + 0x7FFFu + ((ub >> 16) & 1u)) >> 16;
    return ua | (ub << 16);
}
__device__ __forceinline__ uint4 pack8(const float* v) {
    uint4 u;
    u.x = bfpack(v[0], v[1]); u.y = bfpack(v[2], v[3]);
    u.z = bfpack(v[4], v[5]); u.w = bfpack(v[6], v[7]);
    return u;
}
// fp32x4 -> bf16x4 by truncation (P values; <0.4% rel bias; l uses same P)
__device__ __forceinline__ bf16x4 pack4(f32x4 p) {
    union { uint2 u; bf16x4 v; } r;
    r.u.x = __builtin_amdgcn_perm(__float_as_uint(p[1]), __float_as_uint(p[0]), 0x07060302u);
    r.u.y = __builtin_amdgcn_perm(__float_as_uint(p[3]), __float_as_uint(p[2]), 0x07060302u);
    return r.v;
}
__device__ __forceinline__ f32x4 mfma16(bf16x4 a, bf16x4 b, f32x4 c) {
#if __has_builtin(__builtin_amdgcn_mfma_f32_16x16x16bf16_1k)
    return __builtin_amdgcn_mfma_f32_16x16x16bf16_1k(a, b, c, 0, 0, 0);
#else
    bf16x8 a8 = {a[0], a[1], a[2], a[3], 0, 0, 0, 0};
    bf16x8 b8 = {b[0], b[1], b[2], b[3], 0, 0, 0, 0};
    return __builtin_amdgcn_mfma_f32_16x16x32_bf16(a8, b8, c, 0, 0, 0);
#endif
}
__device__ __forceinline__ float fexp2(float x) {
#if __has_builtin(__builtin_amdgcn_exp2f)
    return __builtin_amdgcn_exp2f(x);
#else
    return exp2f(x);
#endif
}

// ---------------- kernel 1: qkv GEMM + border zero + weight pack + bias pack -
// Sequential block ranges (NOT interleaved — R8's interleave polluted the GEMM
// blocks' cache streams):
//   [0, 1296)            qkv GEMM sub-block (nc = bx%3, rowtile = bx/3)
//   [1296, 1811)         zero PAD BORDER of kvp2 (disjoint from qkv writes)
//   [1811, 1856)         pack proj/fc1/fc2 weights -> wpack bf16 frag-linear
//   [1856, 3152)         bias pack fp32 x log2e (MFMA C layout)
#define QKVB 1296
#define ZB   515     // ceil(21952*6/256)
#define WPB  45      // 5760 uint4 / 256 (rounded up)
#define BIASB 1296
__global__ __launch_bounds__(256) void qkvz_kernel(
        const float* __restrict__ X, const float* __restrict__ W,
        const float* __restrict__ bias, const float* __restrict__ lnw,
        const float* __restrict__ lnb,
        const float* __restrict__ projw, const float* __restrict__ fc1w,
        const float* __restrict__ fc2w,
        const int* __restrict__ rpi, const float* __restrict__ rpb,
        unsigned short* __restrict__ q16, unsigned short* __restrict__ kvp2,
        uint4* __restrict__ wpack, float* __restrict__ biasP) {
    __shared__ uint4 Af4[2 * 3 * 4 * 16];   // 6 KB
    __shared__ uint4 Bf4[6 * 3 * 4 * 16];   // 18 KB
    int bx = blockIdx.x, tid = threadIdx.x;

    if (bx >= QKVB + ZB + WPB) {   // ---- bias pack ----
        int b2 = bx - (QKVB + ZB + WPB);   // 0..1295 = head*216 + kt*2 + qh
        int head = b2 / 216;
        int r2 = b2 % 216;
        int kt = r2 >> 1, qh = r2 & 1;
        int k0 = kt * 16;
        int qi = qh * 256 + tid;
        const int* rp = rpi + (long)qi * NKEY + k0;
        int idx[16];
        #pragma unroll
        for (int j = 0; j < 4; ++j) {
            int4 t = *(const int4*)(rp + j * 4);
            idx[j*4+0] = t.x; idx[j*4+1] = t.y; idx[j*4+2] = t.z; idx[j*4+3] = t.w;
        }
        #pragma unroll
        for (int quad = 0; quad < 4; ++quad) {
            float4 v;
            v.x = rpb[idx[quad*4+0] * NHEADS + head] * LOG2E;
            v.y = rpb[idx[quad*4+1] * NHEADS + head] * LOG2E;
            v.z = rpb[idx[quad*4+2] * NHEADS + head] * LOG2E;
            v.w = rpb[idx[quad*4+3] * NHEADS + head] * LOG2E;
            *(float4*)(biasP + ((((long)head*108 + kt)*4 + quad)*512 + qi)*4) = v;
        }
        return;
    }
    if (bx >= QKVB + ZB) {   // ---- weight pack ----
        int u = (bx - QKVB - ZB) * 256 + tid;
        if (u < 5760) {
            int p = (u < 1152) ? u : (u < 3456 ? (u - 1152) % 1152 : (u - 3456) % 1152);
            int nn = p & 15, r = p >> 4, qg = r & 3, r2 = r >> 2;
            int kt = r2 % 3, ct = r2 / 3;
            int n = ct * 16 + nn, g = kt * 4 + qg;
            const float* src;
            if (u < 1152)      src = projw + n * 96 + g * 8;
            else if (u < 3456) { int nc = (u - 1152) / 1152; src = fc1w + (long)(nc * 96 + n) * 96 + g * 8; }
            else               { int kh = (u - 3456) / 1152; src = fc2w + (long)n * 192 + kh * 96 + g * 8; }
            const float4* s4 = (const float4*)src;
            float v[8];
            float4 t0 = s4[0], t1 = s4[1];
            v[0]=t0.x; v[1]=t0.y; v[2]=t0.z; v[3]=t0.w;
            v[4]=t1.x; v[5]=t1.y; v[6]=t1.z; v[7]=t1.w;
            wpack[u] = pack8(v);
        }
        return;
    }
    if (bx >= QKVB) {        // ---- pad-border zero ----
        int t = (bx - QKVB) * 256 + tid;
        if (t < 21952 * 6) {
            int head = t / PD3, pos = t % PD3;
            int d = pos / 784, h = (pos / 28) % 28, w = pos % 28;
            if (d < 2 || d >= 26 || h < 2 || h >= 26 || w < 2 || w >= 26) {
                uint4* p = (uint4*)(kvp2 + ((long)head * PD3 + pos) * 32);
                uint4 z = make_uint4(0, 0, 0, 0);
                p[0] = z; p[1] = z; p[2] = z; p[3] = z;
            }
        }
        return;
    }

    // ---- qkv GEMM sub-block ----
    int nc   = bx % 3;
    int row0 = (bx / 3) * 32;

    if (tid < 128) {   // stage A with LN1: 32 rows, 4 threads/row
        int row = tid >> 2, part = tid & 3;
        int rt = row >> 4, mm = row & 15;
        float v[24];
        const float4* xp = (const float4*)(X + (long)(row0 + row) * 96 + part * 24);
        float s = 0.f, sq = 0.f;
        #pragma unroll
        for (int i = 0; i < 6; ++i) {
            float4 t = xp[i];
            v[i*4+0] = t.x; v[i*4+1] = t.y; v[i*4+2] = t.z; v[i*4+3] = t.w;
            s  += t.x + t.y + t.z + t.w;
            sq += t.x*t.x + t.y*t.y + t.z*t.z + t.w*t.w;
        }
        s  += __shfl_xor(s, 1);  s  += __shfl_xor(s, 2);
        sq += __shfl_xor(sq, 1); sq += __shfl_xor(sq, 2);
        float mean = s * (1.f / 96.f);
        float inv  = rsqrtf(sq * (1.f / 96.f) - mean * mean + 1e-5f);
        const float4* wp = (const float4*)(lnw + part * 24);
        const float4* bp = (const float4*)(lnb + part * 24);
        #pragma unroll
        for (int i = 0; i < 6; ++i) {
            float4 wv = wp[i], bv = bp[i];
            v[i*4+0] = (v[i*4+0] - mean) * inv * wv.x + bv.x;
            v[i*4+1] = (v[i*4+1] - mean) * inv * wv.y + bv.y;
            v[i*4+2] = (v[i*4+2] - mean) * inv * wv.z + bv.z;
            v[i*4+3] = (v[i*4+3] - mean) * inv * wv.w + bv.w;
        }
        #pragma unroll
        for (int gg = 0; gg < 3; ++gg) {
            int g = part * 3 + gg;
            int kt = g >> 2, qq = g & 3;
            Af4[((rt * 3 + kt) * 4 + qq) * 16 + mm] = pack8(v + gg * 8);
        }
    }
    for (int idx = tid; idx < 96 * 12; idx += 256) {
        int n = idx / 12;
        int g = idx % 12;
        const float4* wp = (const float4*)(W + (long)(nc * 96 + n) * 96 + g * 8);
        float v[8];
        float4 t0 = wp[0], t1 = wp[1];
        v[0]=t0.x; v[1]=t0.y; v[2]=t0.z; v[3]=t0.w;
        v[4]=t1.x; v[5]=t1.y; v[6]=t1.z; v[7]=t1.w;
        int ct = n >> 4, nn = n & 15, kt = g >> 2, qg = g & 3;
        Bf4[((ct * 3 + kt) * 4 + qg) * 16 + nn] = pack8(v);
    }
    __syncthreads();

    int wave = tid >> 6, lane = tid & 63;
    int qq = lane >> 4, mI = lane & 15;
    int rt = wave & 1, cg = wave >> 1;

    f32x4 acc[3];
    #pragma unroll
    for (int j = 0; j < 3; ++j) acc[j] = (f32x4){0.f, 0.f, 0.f, 0.f};
    #pragma unroll
    for (int kt = 0; kt < 3; ++kt) {
        bf16x8 a = *(const bf16x8*)&Af4[((rt * 3 + kt) * 4 + qq) * 16 + mI];
        #pragma unroll
        for (int j = 0; j < 3; ++j) {
            bf16x8 b = *(const bf16x8*)&Bf4[(((cg * 3 + j) * 3 + kt) * 4 + qq) * 16 + mI];
            acc[j] = __builtin_amdgcn_mfma_f32_16x16x32_bf16(a, b, acc[j], 0, 0, 0);
        }
    }

    float bv[3];
    #pragma unroll
    for (int j = 0; j < 3; ++j) bv[j] = bias[nc * 96 + (cg * 3 + j) * 16 + mI];
    #pragma unroll
    for (int r = 0; r < 4; ++r) {
        int row = row0 + rt * 16 + qq * 4 + r;
        if (nc == 0) {
            unsigned short* op = q16 + (long)row * 96;
            // 0.25 (hd^-0.5) * log2(e): enables raw v_exp (2^x) in attention
            #pragma unroll
            for (int j = 0; j < 3; ++j)
                op[(cg * 3 + j) * 16 + mI] = bfround(0.25f * LOG2E * (acc[j][r] + bv[j]));
        } else {
            int d = row / 576, hh = (row / 24) % 24, w2 = row % 24;
            long pos = ((long)(d + 2) * 28 + (hh + 2)) * 28 + (w2 + 2);
            #pragma unroll
            for (int j = 0; j < 3; ++j) {
                int head = cg * 3 + j;
                kvp2[((long)head * PD3 + pos) * 32 +
                     (nc == 2 ? 16 : 0) + mI] = bfround(acc[j][r] + bv[j]);
            }
        }
    }
}

// ---------------- kernel 2: MFMA flash attention -----------------------------
// exp2-domain softmax; l on the MFMA pipe (all-ones A). Linear block decode
// (XCD swizzle REVERTED: R11 proved it cuts FETCH 43->29MB but costs ~3us —
// attn is latency-bound, not traffic-bound). Bias single-buffered into bcur.
#define KSTR 20
#define VSTR 68
__global__ __launch_bounds__(256) void attn_kernel(
        const unsigned short* __restrict__ q, const unsigned short* __restrict__ kvp2,
        const float* __restrict__ biasP, float* __restrict__ ao,
        float* __restrict__ lbuf) {
    __shared__ unsigned short Ks[2][64 * KSTR];
    __shared__ unsigned short Vs[2][16 * VSTR];
    int bid = blockIdx.x;                 // 27*6*4*2 = 1296
    int w = bid / 48, rem = bid % 48;
    int head = rem >> 3;
    int quart = (rem >> 1) & 3, half = rem & 1;
    int wd8 = (w / 9) * 8, wh8 = ((w / 3) % 3) * 8, ww8 = (w % 3) * 8;
    int tid = threadIdx.x, wave = tid >> 6, lane = tid & 63;
    int quad = lane >> 4, m16 = lane & 15;
    int key = tid >> 2, part = tid & 3;
    int c0 = half ? 13 : 0;
    int cn = half ? 14 : 13;

    auto kvaddr = [&](int c) -> const uint4* {
        int jg = c * 64 + key;
        int i = jg / 144, jh = (jg / 12) % 12, jw = jg % 12;
        long sp = ((long)(wd8 + i) * PDIM + (wh8 + jh)) * PDIM + (ww8 + jw);
        return (const uint4*)(kvp2 + ((long)head * PD3 + sp) * 32 + part * 8);
    };
    auto writeLDS = [&](int b, uint4 v) {
        if (part < 2) {
            *(uint2*)(&Ks[b][key * KSTR + part * 8])     = make_uint2(v.x, v.y);
            *(uint2*)(&Ks[b][key * KSTR + part * 8 + 4]) = make_uint2(v.z, v.w);
        } else {
            int d0 = (part - 2) * 8;
            Vs[b][(d0+0)*VSTR + key] = (unsigned short)(v.x);
            Vs[b][(d0+1)*VSTR + key] = (unsigned short)(v.x >> 16);
            Vs[b][(d0+2)*VSTR + key] = (unsigned short)(v.y);
            Vs[b][(d0+3)*VSTR + key] = (unsigned short)(v.y >> 16);
            Vs[b][(d0+4)*VSTR + key] = (unsigned short)(v.z);
            Vs[b][(d0+5)*VSTR + key] = (unsigned short)(v.z >> 16);
            Vs[b][(d0+6)*VSTR + key] = (unsigned short)(v.w);
            Vs[b][(d0+7)*VSTR + key] = (unsigned short)(v.w >> 16);
        }
    };

    int grow[2]; bf16x4 qf[2];
    #pragma unroll
    for (int qt = 0; qt < 2; ++qt) {
        int ql = quart * 128 + wave * 32 + qt * 16 + m16;
        int ld = ql >> 6, lh = (ql >> 3) & 7, lw = ql & 7;
        grow[qt] = ((wd8 + ld) * 24 + (wh8 + lh)) * 24 + (ww8 + lw);
        qf[qt] = *(const bf16x4*)(q + (long)grow[qt] * 96 + head * 16 + quad * 4);
    }

    const float* bbase = biasP + (long)head * 884736 + quad * 2048
                         + ((quart * 128 + wave * 32 + m16) << 2);
    f32x4 bcur[2][4];
    #pragma unroll
    for (int qt = 0; qt < 2; ++qt)
        #pragma unroll
        for (int kt = 0; kt < 4; ++kt)
            bcur[qt][kt] = *(const f32x4*)(bbase + (long)(c0*4 + kt) * 8192 + qt * 64);

    writeLDS(0, *kvaddr(c0));

    const bf16x4 onesf = {(short)0x3F80, (short)0x3F80, (short)0x3F80, (short)0x3F80};
    f32x4 o[2], lacc[2];
    o[0] = (f32x4){0.f,0.f,0.f,0.f}; o[1] = (f32x4){0.f,0.f,0.f,0.f};
    lacc[0] = o[0]; lacc[1] = o[1];
    uint4 stgn;

    #pragma unroll 1
    for (int cc = 0; cc < cn; ++cc) {
        int c = c0 + cc;
        if (cc + 1 < cn) stgn = *kvaddr(c + 1);
        __syncthreads();
        int b = cc & 1;

        bf16x4 kf[4];
        #pragma unroll
        for (int kt = 0; kt < 4; ++kt)
            kf[kt] = *(const bf16x4*)(&Ks[b][(kt * 16 + m16) * KSTR + quad * 4]);

        f32x4 S[2][4];
        #pragma unroll
        for (int qt = 0; qt < 2; ++qt)
            #pragma unroll
            for (int kt = 0; kt < 4; ++kt)
                S[qt][kt] = mfma16(kf[kt], qf[qt], bcur[qt][kt]);

        // reload bias for next chunk straight into bcur (anti-dep after S)
        if (cc + 1 < cn) {
            const float* bp = bbase + (long)(c + 1) * 32768;
            #pragma unroll
            for (int qt = 0; qt < 2; ++qt)
                #pragma unroll
                for (int kt = 0; kt < 4; ++kt)
                    bcur[qt][kt] = *(const f32x4*)(bp + kt * 8192 + qt * 64);
        }

        bf16x4 Pb[2][4];
        #pragma unroll
        for (int qt = 0; qt < 2; ++qt)
            #pragma unroll
            for (int kt = 0; kt < 4; ++kt) {
                f32x4 p;
                #pragma unroll
                for (int r = 0; r < 4; ++r) p[r] = fexp2(S[qt][kt][r]);
                Pb[qt][kt] = pack4(p);
                lacc[qt] = mfma16(onesf, Pb[qt][kt], lacc[qt]);
            }

        #pragma unroll
        for (int kt = 0; kt < 4; ++kt) {
            bf16x4 vf = *(const bf16x4*)(&Vs[b][m16 * VSTR + kt * 16 + quad * 4]);
            o[0] = mfma16(vf, Pb[0][kt], o[0]);
            o[1] = mfma16(vf, Pb[1][kt], o[1]);
        }

        if (cc + 1 < cn) writeLDS((cc + 1) & 1, stgn);
    }

    float* aout = ao + (long)half * AOSTR;
    float* lout = lbuf + (long)half * LSTR;
    #pragma unroll
    for (int qt = 0; qt < 2; ++qt) {
        float4* op = (float4*)(aout + (long)grow[qt] * 96 + head * 16 + quad * 4);
        *op = make_float4(o[qt][0], o[qt][1], o[qt][2], o[qt][3]);
        if (quad == 0) lout[grow[qt] * 6 + head] = lacc[qt][0];
    }
}

// ---------------- kernel 3: fused MLP, 512 thr x 64 rows, weights resident ---
#define X2S 100
__global__ __launch_bounds__(512) void mlp_kernel(
        const float* __restrict__ ao0, const float* __restrict__ ao1,
        const float* __restrict__ lbuf, const uint4* __restrict__ wpack,
        const float* __restrict__ projb, const float* __restrict__ x,
        const float* __restrict__ ln2w, const float* __restrict__ ln2b,
        const float* __restrict__ fc1b, const float* __restrict__ fc2b,
        float* __restrict__ out) {
    __shared__ uint4 Ws[5760];               // 92160 B: proj | fc1(2) | fc2(2)
    __shared__ uint4 Af4[4 * 3 * 4 * 16];    // 12288 B
    __shared__ float x2s[64 * X2S];          // 25600 B
    __shared__ unsigned short h16[64 * 192]; // 24576 B  => 154624 B total
    int tid = threadIdx.x;
    int row0 = blockIdx.x * 64;
    int wave = tid >> 6, lane = tid & 63;
    int qq = lane >> 4, mI = lane & 15;
    int rt = wave & 3, cg = wave >> 2;       // 4 row tiles x 2 col groups

    for (int idx = tid; idx < 5760; idx += 512) Ws[idx] = wpack[idx];

    if (tid < 256) {
        int row = tid >> 2, part = tid & 3;
        int rtA = row >> 4, mm = row & 15;
        int grow = row0 + row;
        const float4* a0 = (const float4*)(ao0 + (long)grow * 96 + part * 24);
        const float4* a1 = (const float4*)(ao1 + (long)grow * 96 + part * 24);
        int ha = (part * 3) >> 1, hb = ha + 1;
        float inva = 1.f / (lbuf[grow*6 + ha] + lbuf[LSTR + grow*6 + ha]);
        float invb = 1.f / (lbuf[grow*6 + hb] + lbuf[LSTR + grow*6 + hb]);
        float v[24];
        #pragma unroll
        for (int i = 0; i < 6; ++i) {
            float4 u0 = a0[i], u1 = a1[i];
            #pragma unroll
            for (int j = 0; j < 4; ++j) {
                int gc = part * 24 + i * 4 + j;
                float lv = ((gc >> 4) == ha) ? inva : invb;
                float s = (j==0?u0.x+u1.x : j==1?u0.y+u1.y : j==2?u0.z+u1.z : u0.w+u1.w);
                v[i*4+j] = s * lv;
            }
        }
        #pragma unroll
        for (int gg = 0; gg < 3; ++gg) {
            int g = part * 3 + gg;
            int kt = g >> 2, q4 = g & 3;
            Af4[((rtA * 3 + kt) * 4 + q4) * 16 + mm] = pack8(v + gg * 8);
        }
    }
    __syncthreads();

    {
        f32x4 acc[3];
        #pragma unroll
        for (int j = 0; j < 3; ++j) acc[j] = (f32x4){0.f,0.f,0.f,0.f};
        #pragma unroll
        for (int kt = 0; kt < 3; ++kt) {
            bf16x8 a = *(const bf16x8*)&Af4[((rt * 3 + kt) * 4 + qq) * 16 + mI];
            #pragma unroll
            for (int j = 0; j < 3; ++j) {
                bf16x8 b = *(const bf16x8*)&Ws[(((cg * 3 + j) * 3 + kt) * 4 + qq) * 16 + mI];
                acc[j] = __builtin_amdgcn_mfma_f32_16x16x32_bf16(a, b, acc[j], 0, 0, 0);
            }
        }
        float bv[3];
        #pragma unroll
        for (int j = 0; j < 3; ++j) bv[j] = projb[(cg * 3 + j) * 16 + mI];
        #pragma unroll
        for (int r = 0; r < 4; ++r) {
            int row = rt * 16 + qq * 4 + r;
            int grow = row0 + row;
            #pragma unroll
            for (int j = 0; j < 3; ++j) {
                int col = (cg * 3 + j) * 16 + mI;
                x2s[row * X2S + col] = acc[j][r] + bv[j] + x[(long)grow * 96 + col];
            }
        }
    }
    __syncthreads();

    if (tid < 256) {
        int row = tid >> 2, part = tid & 3;
        int rtA = row >> 4, mm = row & 15;
        float v[24];
        const float4* xp = (const float4*)(x2s + row * X2S + part * 24);
        float s = 0.f, sq = 0.f;
        #pragma unroll
        for (int i = 0; i < 6; ++i) {
            float4 t = xp[i];
            v[i*4+0] = t.x; v[i*4+1] = t.y; v[i*4+2] = t.z; v[i*4+3] = t.w;
            s  += t.x + t.y + t.z + t.w;
            sq += t.x*t.x + t.y*t.y + t.z*t.z + t.w*t.w;
        }
        s  += __shfl_xor(s, 1);  s  += __shfl_xor(s, 2);
        sq += __shfl_xor(sq, 1); sq += __shfl_xor(sq, 2);
        float mean = s * (1.f / 96.f);
        float inv  = rsqrtf(sq * (1.f / 96.f) - mean * mean + 1e-5f);
        const float4* wp = (const float4*)(ln2w + part * 24);
        const float4* bp = (const float4*)(ln2b + part * 24);
        #pragma unroll
        for (int i = 0; i < 6; ++i) {
            float4 wv = wp[i], bv = bp[i];
            v[i*4+0] = (v[i*4+0] - mean) * inv * wv.x + bv.x;
            v[i*4+1] = (v[i*4+1] - mean) * inv * wv.y + bv.y;
            v[i*4+2] = (v[i*4+2] - mean) * inv * wv.z + bv.z;
            v[i*4+3] = (v[i*4+3] - mean) * inv * wv.w + bv.w;
        }
        #pragma unroll
        for (int gg = 0; gg < 3; ++gg) {
            int g = part * 3 + gg;
            int kt = g >> 2, q4 = g & 3;
            Af4[((rtA * 3 + kt) * 4 + q4) * 16 + mm] = pack8(v + gg * 8);
        }
    }
    __syncthreads();

    #pragma unroll
    for (int nc = 0; nc < 2; ++nc) {
        f32x4 acc[3];
        #pragma unroll
        for (int j = 0; j < 3; ++j) acc[j] = (f32x4){0.f,0.f,0.f,0.f};
        #pragma unroll
        for (int kt = 0; kt < 3; ++kt) {
            bf16x8 a = *(const bf16x8*)&Af4[((rt * 3 + kt) * 4 + qq) * 16 + mI];
            #pragma unroll
            for (int j = 0; j < 3; ++j) {
                bf16x8 b = *(const bf16x8*)&Ws[1152 + nc * 1152 +
                               (((cg * 3 + j) * 3 + kt) * 4 + qq) * 16 + mI];
                acc[j] = __builtin_amdgcn_mfma_f32_16x16x32_bf16(a, b, acc[j], 0, 0, 0);
            }
        }
        float bv[3];
        #pragma unroll
        for (int j = 0; j < 3; ++j) bv[j] = fc1b[nc * 96 + (cg * 3 + j) * 16 + mI];
        #pragma unroll
        for (int r = 0; r < 4; ++r) {
            int row = rt * 16 + qq * 4 + r;
            #pragma unroll
            for (int j = 0; j < 3; ++j) {
                int col = nc * 96 + (cg * 3 + j) * 16 + mI;
                float v = acc[j][r] + bv[j];
                float g = 0.5f * v * (1.f + erff(v * 0.70710678f));
                int fi = (((row >> 4) * 6 + (col >> 5)) * 4 + ((col >> 3) & 3)) * 16 + (row & 15);
                h16[fi * 8 + (col & 7)] = bfround(g);
            }
        }
    }
    __syncthreads();

    f32x4 acc2[3];
    #pragma unroll
    for (int j = 0; j < 3; ++j) acc2[j] = (f32x4){0.f,0.f,0.f,0.f};
    #pragma unroll
    for (int kh = 0; kh < 2; ++kh) {
        #pragma unroll
        for (int kt = 0; kt < 3; ++kt) {
            int ktA = kh * 3 + kt;
            bf16x8 a = *(const bf16x8*)&h16[(((rt * 6 + ktA) * 4 + qq) * 16 + mI) * 8];
            #pragma unroll
            for (int j = 0; j < 3; ++j) {
                bf16x8 b = *(const bf16x8*)&Ws[3456 + kh * 1152 +
                               (((cg * 3 + j) * 3 + kt) * 4 + qq) * 16 + mI];
                acc2[j] = __builtin_amdgcn_mfma_f32_16x16x32_bf16(a, b, acc2[j], 0, 0, 0);
            }
        }
    }
    float bv[3];
    #pragma unroll
    for (int j = 0; j < 3; ++j) bv[j] = fc2b[(cg * 3 + j) * 16 + mI];
    #pragma unroll
    for (int r = 0; r < 4; ++r) {
        int row = rt * 16 + qq * 4 + r;
        int grow = row0 + row;
        #pragma unroll
        for (int j = 0; j < 3; ++j) {
            int col = (cg * 3 + j) * 16 + mI;
            out[(long)grow * 96 + col] = acc2[j][r] + bv[j] + x2s[row * X2S + col];
        }
    }
}

// ---------------- launcher ---------------------------------------------------
extern "C" void kernel_launch(void* const* d_in, const int* in_sizes, int n_in,
                              void* d_out, int out_size, void* d_ws, size_t ws_size,
                              hipStream_t stream) {
    const float* x     = (const float*)d_in[0];
    const float* ln1w  = (const float*)d_in[1];
    const float* ln1b  = (const float*)d_in[2];
    const float* qkvw  = (const float*)d_in[3];
    const float* qkvb  = (const float*)d_in[4];
    const float* rpb   = (const float*)d_in[5];
    const float* projw = (const float*)d_in[6];
    const float* projb = (const float*)d_in[7];
    const float* ln2w  = (const float*)d_in[8];
    const float* ln2b  = (const float*)d_in[9];
    const float* fc1w  = (const float*)d_in[10];
    const float* fc1b  = (const float*)d_in[11];
    const float* fc2w  = (const float*)d_in[12];
    const float* fc2b  = (const float*)d_in[13];
    const int*   rpi   = (const int*)d_in[14];
    float* outp = (float*)d_out;

    float* ws = (float*)d_ws;
    float*          aop    = ws;                               // 2 x 1,327,104 f
    unsigned short* q16    = (unsigned short*)(ws + 2654208);  // 663,552 f
    unsigned short* kvp16  = (unsigned short*)(ws + 3317760);  // 2,107,392 f
    float*          biasPf = ws + 5425152;                     // 5,308,416 f (fp32)
    float*          lbuf   = ws + 10733568;                    // 165,888 f
    uint4*          wpack  = (uint4*)(ws + 10899456);          // 23,040 f (5760 u4)

    qkvz_kernel<<<QKVB + ZB + WPB + BIASB, 256, 0, stream>>>(
        x, qkvw, qkvb, ln1w, ln1b, projw, fc1w, fc2w, rpi, rpb,
        q16, kvp16, wpack, biasPf);
    attn_kernel<<<NWIN * NHEADS * 4 * 2, 256, 0, stream>>>(q16, kvp16, biasPf, aop, lbuf);
    mlp_kernel<<<LTOK / 64, 512, 0, stream>>>(aop, aop + AOSTR, lbuf, wpack, projb, x,
                                              ln2w, ln2b, fc1b, fc2b, outp);
}

// Round 13
// 170.232 us; speedup vs baseline: 1.0902x; 1.0558x over previous
//
#include <hip/hip_runtime.h>
#include <math.h>

// Problem constants (from reference)
#define DIMC   96
#define NHEADS 6
#define HD     16
#define WSZ    8
#define OWSZ   12
#define PADW   2
#define DD     24
#define LTOK   13824      // 24^3
#define NWIN   27         // 3^3
#define NKEY   1728       // 12^3
#define NROW   512        // 8^3
#define MLPH   192
#define PDIM   28         // 24 + 2*2
#define PD3    21952      // 28^3
#define TBL    6859       // 19^3
#define LSTR   82944      // 13824*6 (lbuf per-half stride)
#define AOSTR  1327104    // 13824*96 (ao per-half stride)
#define LOG2E  1.4426950408889634f

typedef __attribute__((ext_vector_type(4))) short bf16x4;
typedef __attribute__((ext_vector_type(8))) short bf16x8;
typedef __attribute__((ext_vector_type(4))) float f32x4;

// ---------------- helpers ----------------------------------------------------
__device__ __forceinline__ unsigned short bfround(float f) {
    unsigned u = __float_as_uint(f);
    return (unsigned short)((u + 0x7FFFu + ((u >> 16) & 1u)) >> 16);
}
__device__ __forceinline__ unsigned bfpack(float a, float b) {
    unsigned ua = __float_as_uint(a), ub = __float_as_uint(b);
    ua = (ua + 0x7FFFu + ((ua >> 16) & 1u)) >> 16;
    ub = (ub + 0x7FFFu + ((ub >> 16) & 1u)) >> 16;
    return ua | (ub << 16);
}
__device__ __forceinline__ uint4 pack8(const float* v) {
    uint4 u;
    u.x = bfpack(v[0], v[1]); u.y = bfpack(v[2], v[3]);
    u.z = bfpack(v[4], v[5]); u.w = bfpack(v[6], v[7]);
    return u;
}
// fp32x4 -> bf16x4 by truncation (P values; <0.4% rel bias; l uses same P)
__device__ __forceinline__ bf16x4 pack4(f32x4 p) {
    union { uint2 u; bf16x4 v; } r;
    r.u.x = __builtin_amdgcn_perm(__float_as_uint(p[1]), __float_as_uint(p[0]), 0x07060302u);
    r.u.y = __builtin_amdgcn_perm(__float_as_uint(p[3]), __float_as_uint(p[2]), 0x07060302u);
    return r.v;
}
__device__ __forceinline__ f32x4 mfma16(bf16x4 a, bf16x4 b, f32x4 c) {
#if __has_builtin(__builtin_amdgcn_mfma_f32_16x16x16bf16_1k)
    return __builtin_amdgcn_mfma_f32_16x16x16bf16_1k(a, b, c, 0, 0, 0);
#else
    bf16x8 a8 = {a[0], a[1], a[2], a[3], 0, 0, 0, 0};
    bf16x8 b8 = {b[0], b[1], b[2], b[3], 0, 0, 0, 0};
    return __builtin_amdgcn_mfma_f32_16x16x32_bf16(a8, b8, c, 0, 0, 0);
#endif
}
__device__ __forceinline__ float fexp2(float x) {
#if __has_builtin(__builtin_amdgcn_exp2f)
    return __builtin_amdgcn_exp2f(x);
#else
    return exp2f(x);
#endif
}

// ---------------- kernel 1: qkv GEMM + border zero + weight pack + bias pack -
// Sequential block ranges:
//   [0, 1296)            qkv GEMM sub-block (nc = bx%3, rowtile = bx/3)
//   [1296, 1811)         zero PAD BORDER of kvp2 (disjoint from qkv writes)
//   [1811, 1856)         pack proj/fc1/fc2 weights -> wpack bf16 frag-linear
//   [1856, 2072)         bias pack, ALL 6 HEADS per block (rpi read once;
//                        rpb gathers for 6 heads hit the same 24-B lines)
#define QKVB 1296
#define ZB   515     // ceil(21952*6/256)
#define WPB  45      // 5760 uint4 / 256 (rounded up)
#define BIASB 216
__global__ __launch_bounds__(256) void qkvz_kernel(
        const float* __restrict__ X, const float* __restrict__ W,
        const float* __restrict__ bias, const float* __restrict__ lnw,
        const float* __restrict__ lnb,
        const float* __restrict__ projw, const float* __restrict__ fc1w,
        const float* __restrict__ fc2w,
        const int* __restrict__ rpi, const float* __restrict__ rpb,
        unsigned short* __restrict__ q16, unsigned short* __restrict__ kvp2,
        uint4* __restrict__ wpack, float* __restrict__ biasP) {
    __shared__ uint4 Af4[2 * 3 * 4 * 16];   // 6 KB
    __shared__ uint4 Bf4[6 * 3 * 4 * 16];   // 18 KB
    int bx = blockIdx.x, tid = threadIdx.x;

    if (bx >= QKVB + ZB + WPB) {   // ---- bias pack (6 heads/block) ----
        int b2 = bx - (QKVB + ZB + WPB);   // 0..215 = kt*2 + qh
        int kt = b2 >> 1, qh = b2 & 1;
        int k0 = kt * 16;
        int qi = qh * 256 + tid;
        const int* rp = rpi + (long)qi * NKEY + k0;
        int idx[16];
        #pragma unroll
        for (int j = 0; j < 4; ++j) {
            int4 t = *(const int4*)(rp + j * 4);
            idx[j*4+0] = t.x * NHEADS; idx[j*4+1] = t.y * NHEADS;
            idx[j*4+2] = t.z * NHEADS; idx[j*4+3] = t.w * NHEADS;
        }
        #pragma unroll
        for (int head = 0; head < NHEADS; ++head) {
            #pragma unroll
            for (int quad = 0; quad < 4; ++quad) {
                float4 v;
                v.x = rpb[idx[quad*4+0] + head] * LOG2E;
                v.y = rpb[idx[quad*4+1] + head] * LOG2E;
                v.z = rpb[idx[quad*4+2] + head] * LOG2E;
                v.w = rpb[idx[quad*4+3] + head] * LOG2E;
                *(float4*)(biasP + ((((long)head*108 + kt)*4 + quad)*512 + qi)*4) = v;
            }
        }
        return;
    }
    if (bx >= QKVB + ZB) {   // ---- weight pack ----
        int u = (bx - QKVB - ZB) * 256 + tid;
        if (u < 5760) {
            int p = (u < 1152) ? u : (u < 3456 ? (u - 1152) % 1152 : (u - 3456) % 1152);
            int nn = p & 15, r = p >> 4, qg = r & 3, r2 = r >> 2;
            int kt = r2 % 3, ct = r2 / 3;
            int n = ct * 16 + nn, g = kt * 4 + qg;
            const float* src;
            if (u < 1152)      src = projw + n * 96 + g * 8;
            else if (u < 3456) { int nc = (u - 1152) / 1152; src = fc1w + (long)(nc * 96 + n) * 96 + g * 8; }
            else               { int kh = (u - 3456) / 1152; src = fc2w + (long)n * 192 + kh * 96 + g * 8; }
            const float4* s4 = (const float4*)src;
            float v[8];
            float4 t0 = s4[0], t1 = s4[1];
            v[0]=t0.x; v[1]=t0.y; v[2]=t0.z; v[3]=t0.w;
            v[4]=t1.x; v[5]=t1.y; v[6]=t1.z; v[7]=t1.w;
            wpack[u] = pack8(v);
        }
        return;
    }
    if (bx >= QKVB) {        // ---- pad-border zero ----
        int t = (bx - QKVB) * 256 + tid;
        if (t < 21952 * 6) {
            int head = t / PD3, pos = t % PD3;
            int d = pos / 784, h = (pos / 28) % 28, w = pos % 28;
            if (d < 2 || d >= 26 || h < 2 || h >= 26 || w < 2 || w >= 26) {
                uint4* p = (uint4*)(kvp2 + ((long)head * PD3 + pos) * 32);
                uint4 z = make_uint4(0, 0, 0, 0);
                p[0] = z; p[1] = z; p[2] = z; p[3] = z;
            }
        }
        return;
    }

    // ---- qkv GEMM sub-block ----
    int nc   = bx % 3;
    int row0 = (bx / 3) * 32;

    if (tid < 128) {   // stage A with LN1: 32 rows, 4 threads/row
        int row = tid >> 2, part = tid & 3;
        int rt = row >> 4, mm = row & 15;
        float v[24];
        const float4* xp = (const float4*)(X + (long)(row0 + row) * 96 + part * 24);
        float s = 0.f, sq = 0.f;
        #pragma unroll
        for (int i = 0; i < 6; ++i) {
            float4 t = xp[i];
            v[i*4+0] = t.x; v[i*4+1] = t.y; v[i*4+2] = t.z; v[i*4+3] = t.w;
            s  += t.x + t.y + t.z + t.w;
            sq += t.x*t.x + t.y*t.y + t.z*t.z + t.w*t.w;
        }
        s  += __shfl_xor(s, 1);  s  += __shfl_xor(s, 2);
        sq += __shfl_xor(sq, 1); sq += __shfl_xor(sq, 2);
        float mean = s * (1.f / 96.f);
        float inv  = rsqrtf(sq * (1.f / 96.f) - mean * mean + 1e-5f);
        const float4* wp = (const float4*)(lnw + part * 24);
        const float4* bp = (const float4*)(lnb + part * 24);
        #pragma unroll
        for (int i = 0; i < 6; ++i) {
            float4 wv = wp[i], bv = bp[i];
            v[i*4+0] = (v[i*4+0] - mean) * inv * wv.x + bv.x;
            v[i*4+1] = (v[i*4+1] - mean) * inv * wv.y + bv.y;
            v[i*4+2] = (v[i*4+2] - mean) * inv * wv.z + bv.z;
            v[i*4+3] = (v[i*4+3] - mean) * inv * wv.w + bv.w;
        }
        #pragma unroll
        for (int gg = 0; gg < 3; ++gg) {
            int g = part * 3 + gg;
            int kt = g >> 2, qq = g & 3;
            Af4[((rt * 3 + kt) * 4 + qq) * 16 + mm] = pack8(v + gg * 8);
        }
    }
    for (int idx = tid; idx < 96 * 12; idx += 256) {
        int n = idx / 12;
        int g = idx % 12;
        const float4* wp = (const float4*)(W + (long)(nc * 96 + n) * 96 + g * 8);
        float v[8];
        float4 t0 = wp[0], t1 = wp[1];
        v[0]=t0.x; v[1]=t0.y; v[2]=t0.z; v[3]=t0.w;
        v[4]=t1.x; v[5]=t1.y; v[6]=t1.z; v[7]=t1.w;
        int ct = n >> 4, nn = n & 15, kt = g >> 2, qg = g & 3;
        Bf4[((ct * 3 + kt) * 4 + qg) * 16 + nn] = pack8(v);
    }
    __syncthreads();

    int wave = tid >> 6, lane = tid & 63;
    int qq = lane >> 4, mI = lane & 15;
    int rt = wave & 1, cg = wave >> 1;

    f32x4 acc[3];
    #pragma unroll
    for (int j = 0; j < 3; ++j) acc[j] = (f32x4){0.f, 0.f, 0.f, 0.f};
    #pragma unroll
    for (int kt = 0; kt < 3; ++kt) {
        bf16x8 a = *(const bf16x8*)&Af4[((rt * 3 + kt) * 4 + qq) * 16 + mI];
        #pragma unroll
        for (int j = 0; j < 3; ++j) {
            bf16x8 b = *(const bf16x8*)&Bf4[(((cg * 3 + j) * 3 + kt) * 4 + qq) * 16 + mI];
            acc[j] = __builtin_amdgcn_mfma_f32_16x16x32_bf16(a, b, acc[j], 0, 0, 0);
        }
    }

    float bv[3];
    #pragma unroll
    for (int j = 0; j < 3; ++j) bv[j] = bias[nc * 96 + (cg * 3 + j) * 16 + mI];
    #pragma unroll
    for (int r = 0; r < 4; ++r) {
        int row = row0 + rt * 16 + qq * 4 + r;
        if (nc == 0) {
            unsigned short* op = q16 + (long)row * 96;
            // 0.25 (hd^-0.5) * log2(e): enables raw v_exp (2^x) in attention
            #pragma unroll
            for (int j = 0; j < 3; ++j)
                op[(cg * 3 + j) * 16 + mI] = bfround(0.25f * LOG2E * (acc[j][r] + bv[j]));
        } else {
            int d = row / 576, hh = (row / 24) % 24, w2 = row % 24;
            long pos = ((long)(d + 2) * 28 + (hh + 2)) * 28 + (w2 + 2);
            #pragma unroll
            for (int j = 0; j < 3; ++j) {
                int head = cg * 3 + j;
                kvp2[((long)head * PD3 + pos) * 32 +
                     (nc == 2 ? 16 : 0) + mI] = bfround(acc[j][r] + bv[j]);
            }
        }
    }
}

// ---------------- kernel 2: MFMA flash attention -----------------------------
// O = P·V formulation: the S^T MFMA's C-layout output IS the A-operand layout
// of P[q][key] (lane(quad,m16) reg r = S^T[key=quad*4+r][q=m16] = A[m][k]) so
// P feeds PV as A with zero shuffles, V stays ROW-MAJOR in LDS (staging writes
// = cheap uint2, no b16 scatter transpose; the transpose moved to 4 u16 reads
// per kt per wave — 10x fewer ops). l via ones as B (row-sum over keys).
// Bias register double-buffer (bnxt) RESTORED: R10=50.0 vs R12 single=52.4.
#define KSTR 20
#define VST2 22   // V row stride (shorts): quads hit disjoint bank ranges
__global__ __launch_bounds__(256) void attn_kernel(
        const unsigned short* __restrict__ q, const unsigned short* __restrict__ kvp2,
        const float* __restrict__ biasP, float* __restrict__ ao,
        float* __restrict__ lbuf) {
    __shared__ unsigned short Ks[2][64 * KSTR];
    __shared__ unsigned short Vs[2][64 * VST2];
    int bid = blockIdx.x;                 // 27*6*4*2 = 1296
    int w = bid / 48, rem = bid % 48;
    int head = rem >> 3;
    int quart = (rem >> 1) & 3, half = rem & 1;
    int wd8 = (w / 9) * 8, wh8 = ((w / 3) % 3) * 8, ww8 = (w % 3) * 8;
    int tid = threadIdx.x, wave = tid >> 6, lane = tid & 63;
    int quad = lane >> 4, m16 = lane & 15;
    int key = tid >> 2, part = tid & 3;
    int c0 = half ? 13 : 0;
    int cn = half ? 14 : 13;

    auto kvaddr = [&](int c) -> const uint4* {
        int jg = c * 64 + key;
        int i = jg / 144, jh = (jg / 12) % 12, jw = jg % 12;
        long sp = ((long)(wd8 + i) * PDIM + (wh8 + jh)) * PDIM + (ww8 + jw);
        return (const uint4*)(kvp2 + ((long)head * PD3 + sp) * 32 + part * 8);
    };
    auto writeLDS = [&](int b, uint4 v) {
        if (part < 2) {
            *(uint2*)(&Ks[b][key * KSTR + part * 8])     = make_uint2(v.x, v.y);
            *(uint2*)(&Ks[b][key * KSTR + part * 8 + 4]) = make_uint2(v.z, v.w);
        } else {
            int d0 = (part - 2) * 8;
            *(uint2*)(&Vs[b][key * VST2 + d0])     = make_uint2(v.x, v.y);
            *(uint2*)(&Vs[b][key * VST2 + d0 + 4]) = make_uint2(v.z, v.w);
        }
    };

    bf16x4 qf[2];
    #pragma unroll
    for (int qt = 0; qt < 2; ++qt) {
        int ql = quart * 128 + wave * 32 + qt * 16 + m16;
        int ld = ql >> 6, lh = (ql >> 3) & 7, lw = ql & 7;
        int g = ((wd8 + ld) * 24 + (wh8 + lh)) * 24 + (ww8 + lw);
        qf[qt] = *(const bf16x4*)(q + (long)g * 96 + head * 16 + quad * 4);
    }

    const float* bbase = biasP + (long)head * 884736 + quad * 2048
                         + ((quart * 128 + wave * 32 + m16) << 2);
    f32x4 bcur[2][4];
    #pragma unroll
    for (int qt = 0; qt < 2; ++qt)
        #pragma unroll
        for (int kt = 0; kt < 4; ++kt)
            bcur[qt][kt] = *(const f32x4*)(bbase + (long)(c0*4 + kt) * 8192 + qt * 64);

    writeLDS(0, *kvaddr(c0));

    const bf16x4 onesf = {(short)0x3F80, (short)0x3F80, (short)0x3F80, (short)0x3F80};
    f32x4 o[2], lacc[2];
    o[0] = (f32x4){0.f,0.f,0.f,0.f}; o[1] = (f32x4){0.f,0.f,0.f,0.f};
    lacc[0] = o[0]; lacc[1] = o[1];
    uint4 stgn;

    #pragma unroll 1
    for (int cc = 0; cc < cn; ++cc) {
        int c = c0 + cc;
        if (cc + 1 < cn) stgn = *kvaddr(c + 1);
        __syncthreads();
        int b = cc & 1;

        bf16x4 kf[4];
        #pragma unroll
        for (int kt = 0; kt < 4; ++kt)
            kf[kt] = *(const bf16x4*)(&Ks[b][(kt * 16 + m16) * KSTR + quad * 4]);

        f32x4 S[2][4];
        #pragma unroll
        for (int qt = 0; qt < 2; ++qt)
            #pragma unroll
            for (int kt = 0; kt < 4; ++kt)
                S[qt][kt] = mfma16(kf[kt], qf[qt], bcur[qt][kt]);

        f32x4 bnxt[2][4];
        if (cc + 1 < cn) {
            const float* bp = bbase + (long)(c + 1) * 32768;
            #pragma unroll
            for (int qt = 0; qt < 2; ++qt)
                #pragma unroll
                for (int kt = 0; kt < 4; ++kt)
                    bnxt[qt][kt] = *(const f32x4*)(bp + kt * 8192 + qt * 64);
        }

        bf16x4 Pb[2][4];
        #pragma unroll
        for (int qt = 0; qt < 2; ++qt)
            #pragma unroll
            for (int kt = 0; kt < 4; ++kt) {
                f32x4 p;
                #pragma unroll
                for (int r = 0; r < 4; ++r) p[r] = fexp2(S[qt][kt][r]);
                Pb[qt][kt] = pack4(p);
                lacc[qt] = mfma16(Pb[qt][kt], onesf, lacc[qt]);
            }

        #pragma unroll
        for (int kt = 0; kt < 4; ++kt) {
            // B-operand of O=P·V from row-major Vs: B[k=quad*4+j][n=m16]
            union { unsigned short s[4]; bf16x4 v; } u;
            int base = (kt * 16 + quad * 4) * VST2 + m16;
            u.s[0] = Vs[b][base];
            u.s[1] = Vs[b][base + VST2];
            u.s[2] = Vs[b][base + 2 * VST2];
            u.s[3] = Vs[b][base + 3 * VST2];
            o[0] = mfma16(Pb[0][kt], u.v, o[0]);
            o[1] = mfma16(Pb[1][kt], u.v, o[1]);
        }

        if (cc + 1 < cn) writeLDS((cc + 1) & 1, stgn);
        #pragma unroll
        for (int qt = 0; qt < 2; ++qt)
            #pragma unroll
            for (int kt = 0; kt < 4; ++kt) bcur[qt][kt] = bnxt[qt][kt];
    }

    // epilogue: O in C layout [q=quad*4+r][dim=m16]
    float* aout = ao + (long)half * AOSTR;
    float* lout = lbuf + (long)half * LSTR;
    #pragma unroll
    for (int qt = 0; qt < 2; ++qt) {
        #pragma unroll
        for (int r = 0; r < 4; ++r) {
            int ql = quart * 128 + wave * 32 + qt * 16 + quad * 4 + r;
            int ld = ql >> 6, lh = (ql >> 3) & 7, lw = ql & 7;
            int g = ((wd8 + ld) * 24 + (wh8 + lh)) * 24 + (ww8 + lw);
            aout[(long)g * 96 + head * 16 + m16] = o[qt][r];
            if (m16 == 0) lout[g * 6 + head] = lacc[qt][r];
        }
    }
}

// ---------------- kernel 3: fused MLP, 512 thr x 64 rows, weights resident ---
#define X2S 100
__global__ __launch_bounds__(512) void mlp_kernel(
        const float* __restrict__ ao0, const float* __restrict__ ao1,
        const float* __restrict__ lbuf, const uint4* __restrict__ wpack,
        const float* __restrict__ projb, const float* __restrict__ x,
        const float* __restrict__ ln2w, const float* __restrict__ ln2b,
        const float* __restrict__ fc1b, const float* __restrict__ fc2b,
        float* __restrict__ out) {
    __shared__ uint4 Ws[5760];               // 92160 B: proj | fc1(2) | fc2(2)
    __shared__ uint4 Af4[4 * 3 * 4 * 16];    // 12288 B
    __shared__ float x2s[64 * X2S];          // 25600 B
    __shared__ unsigned short h16[64 * 192]; // 24576 B  => 154624 B total
    int tid = threadIdx.x;
    int row0 = blockIdx.x * 64;
    int wave = tid >> 6, lane = tid & 63;
    int qq = lane >> 4, mI = lane & 15;
    int rt = wave & 3, cg = wave >> 2;       // 4 row tiles x 2 col groups

    for (int idx = tid; idx < 5760; idx += 512) Ws[idx] = wpack[idx];

    if (tid < 256) {
        int row = tid >> 2, part = tid & 3;
        int rtA = row >> 4, mm = row & 15;
        int grow = row0 + row;
        const float4* a0 = (const float4*)(ao0 + (long)grow * 96 + part * 24);
        const float4* a1 = (const float4*)(ao1 + (long)grow * 96 + part * 24);
        int ha = (part * 3) >> 1, hb = ha + 1;
        float inva = 1.f / (lbuf[grow*6 + ha] + lbuf[LSTR + grow*6 + ha]);
        float invb = 1.f / (lbuf[grow*6 + hb] + lbuf[LSTR + grow*6 + hb]);
        float v[24];
        #pragma unroll
        for (int i = 0; i < 6; ++i) {
            float4 u0 = a0[i], u1 = a1[i];
            #pragma unroll
            for (int j = 0; j < 4; ++j) {
                int gc = part * 24 + i * 4 + j;
                float lv = ((gc >> 4) == ha) ? inva : invb;
                float s = (j==0?u0.x+u1.x : j==1?u0.y+u1.y : j==2?u0.z+u1.z : u0.w+u1.w);
                v[i*4+j] = s * lv;
            }
        }
        #pragma unroll
        for (int gg = 0; gg < 3; ++gg) {
            int g = part * 3 + gg;
            int kt = g >> 2, q4 = g & 3;
            Af4[((rtA * 3 + kt) * 4 + q4) * 16 + mm] = pack8(v + gg * 8);
        }
    }
    __syncthreads();

    {
        f32x4 acc[3];
        #pragma unroll
        for (int j = 0; j < 3; ++j) acc[j] = (f32x4){0.f,0.f,0.f,0.f};
        #pragma unroll
        for (int kt = 0; kt < 3; ++kt) {
            bf16x8 a = *(const bf16x8*)&Af4[((rt * 3 + kt) * 4 + qq) * 16 + mI];
            #pragma unroll
            for (int j = 0; j < 3; ++j) {
                bf16x8 b = *(const bf16x8*)&Ws[(((cg * 3 + j) * 3 + kt) * 4 + qq) * 16 + mI];
                acc[j] = __builtin_amdgcn_mfma_f32_16x16x32_bf16(a, b, acc[j], 0, 0, 0);
            }
        }
        float bv[3];
        #pragma unroll
        for (int j = 0; j < 3; ++j) bv[j] = projb[(cg * 3 + j) * 16 + mI];
        #pragma unroll
        for (int r = 0; r < 4; ++r) {
            int row = rt * 16 + qq * 4 + r;
            int grow = row0 + row;
            #pragma unroll
            for (int j = 0; j < 3; ++j) {
                int col = (cg * 3 + j) * 16 + mI;
                x2s[row * X2S + col] = acc[j][r] + bv[j] + x[(long)grow * 96 + col];
            }
        }
    }
    __syncthreads();

    if (tid < 256) {
        int row = tid >> 2, part = tid & 3;
        int rtA = row >> 4, mm = row & 15;
        float v[24];
        const float4* xp = (const float4*)(x2s + row * X2S + part * 24);
        float s = 0.f, sq = 0.f;
        #pragma unroll
        for (int i = 0; i < 6; ++i) {
            float4 t = xp[i];
            v[i*4+0] = t.x; v[i*4+1] = t.y; v[i*4+2] = t.z; v[i*4+3] = t.w;
            s  += t.x + t.y + t.z + t.w;
            sq += t.x*t.x + t.y*t.y + t.z*t.z + t.w*t.w;
        }
        s  += __shfl_xor(s, 1);  s  += __shfl_xor(s, 2);
        sq += __shfl_xor(sq, 1); sq += __shfl_xor(sq, 2);
        float mean = s * (1.f / 96.f);
        float inv  = rsqrtf(sq * (1.f / 96.f) - mean * mean + 1e-5f);
        const float4* wp = (const float4*)(ln2w + part * 24);
        const float4* bp = (const float4*)(ln2b + part * 24);
        #pragma unroll
        for (int i = 0; i < 6; ++i) {
            float4 wv = wp[i], bv = bp[i];
            v[i*4+0] = (v[i*4+0] - mean) * inv * wv.x + bv.x;
            v[i*4+1] = (v[i*4+1] - mean) * inv * wv.y + bv.y;
            v[i*4+2] = (v[i*4+2] - mean) * inv * wv.z + bv.z;
            v[i*4+3] = (v[i*4+3] - mean) * inv * wv.w + bv.w;
        }
        #pragma unroll
        for (int gg = 0; gg < 3; ++gg) {
            int g = part * 3 + gg;
            int kt = g >> 2, q4 = g & 3;
            Af4[((rtA * 3 + kt) * 4 + q4) * 16 + mm] = pack8(v + gg * 8);
        }
    }
    __syncthreads();

    #pragma unroll
    for (int nc = 0; nc < 2; ++nc) {
        f32x4 acc[3];
        #pragma unroll
        for (int j = 0; j < 3; ++j) acc[j] = (f32x4){0.f,0.f,0.f,0.f};
        #pragma unroll
        for (int kt = 0; kt < 3; ++kt) {
            bf16x8 a = *(const bf16x8*)&Af4[((rt * 3 + kt) * 4 + qq) * 16 + mI];
            #pragma unroll
            for (int j = 0; j < 3; ++j) {
                bf16x8 b = *(const bf16x8*)&Ws[1152 + nc * 1152 +
                               (((cg * 3 + j) * 3 + kt) * 4 + qq) * 16 + mI];
                acc[j] = __builtin_amdgcn_mfma_f32_16x16x32_bf16(a, b, acc[j], 0, 0, 0);
            }
        }
        float bv[3];
        #pragma unroll
        for (int j = 0; j < 3; ++j) bv[j] = fc1b[nc * 96 + (cg * 3 + j) * 16 + mI];
        #pragma unroll
        for (int r = 0; r < 4; ++r) {
            int row = rt * 16 + qq * 4 + r;
            #pragma unroll
            for (int j = 0; j < 3; ++j) {
                int col = nc * 96 + (cg * 3 + j) * 16 + mI;
                float v = acc[j][r] + bv[j];
                float g = 0.5f * v * (1.f + erff(v * 0.70710678f));
                int fi = (((row >> 4) * 6 + (col >> 5)) * 4 + ((col >> 3) & 3)) * 16 + (row & 15);
                h16[fi * 8 + (col & 7)] = bfround(g);
            }
        }
    }
    __syncthreads();

    f32x4 acc2[3];
    #pragma unroll
    for (int j = 0; j < 3; ++j) acc2[j] = (f32x4){0.f,0.f,0.f,0.f};
    #pragma unroll
    for (int kh = 0; kh < 2; ++kh) {
        #pragma unroll
        for (int kt = 0; kt < 3; ++kt) {
            int ktA = kh * 3 + kt;
            bf16x8 a = *(const bf16x8*)&h16[(((rt * 6 + ktA) * 4 + qq) * 16 + mI) * 8];
            #pragma unroll
            for (int j = 0; j < 3; ++j) {
                bf16x8 b = *(const bf16x8*)&Ws[3456 + kh * 1152 +
                               (((cg * 3 + j) * 3 + kt) * 4 + qq) * 16 + mI];
                acc2[j] = __builtin_amdgcn_mfma_f32_16x16x32_bf16(a, b, acc2[j], 0, 0, 0);
            }
        }
    }
    float bv[3];
    #pragma unroll
    for (int j = 0; j < 3; ++j) bv[j] = fc2b[(cg * 3 + j) * 16 + mI];
    #pragma unroll
    for (int r = 0; r < 4; ++r) {
        int row = rt * 16 + qq * 4 + r;
        int grow = row0 + row;
        #pragma unroll
        for (int j = 0; j < 3; ++j) {
            int col = (cg * 3 + j) * 16 + mI;
            out[(long)grow * 96 + col] = acc2[j][r] + bv[j] + x2s[row * X2S + col];
        }
    }
}

// ---------------- launcher ---------------------------------------------------
extern "C" void kernel_launch(void* const* d_in, const int* in_sizes, int n_in,
                              void* d_out, int out_size, void* d_ws, size_t ws_size,
                              hipStream_t stream) {
    const float* x     = (const float*)d_in[0];
    const float* ln1w  = (const float*)d_in[1];
    const float* ln1b  = (const float*)d_in[2];
    const float* qkvw  = (const float*)d_in[3];
    const float* qkvb  = (const float*)d_in[4];
    const float* rpb   = (const float*)d_in[5];
    const float* projw = (const float*)d_in[6];
    const float* projb = (const float*)d_in[7];
    const float* ln2w  = (const float*)d_in[8];
    const float* ln2b  = (const float*)d_in[9];
    const float* fc1w  = (const float*)d_in[10];
    const float* fc1b  = (const float*)d_in[11];
    const float* fc2w  = (const float*)d_in[12];
    const float* fc2b  = (const float*)d_in[13];
    const int*   rpi   = (const int*)d_in[14];
    float* outp = (float*)d_out;

    float* ws = (float*)d_ws;
    float*          aop    = ws;                               // 2 x 1,327,104 f
    unsigned short* q16    = (unsigned short*)(ws + 2654208);  // 663,552 f
    unsigned short* kvp16  = (unsigned short*)(ws + 3317760);  // 2,107,392 f
    float*          biasPf = ws + 5425152;                     // 5,308,416 f (fp32)
    float*          lbuf   = ws + 10733568;                    // 165,888 f
    uint4*          wpack  = (uint4*)(ws + 10899456);          // 23,040 f (5760 u4)

    qkvz_kernel<<<QKVB + ZB + WPB + BIASB, 256, 0, stream>>>(
        x, qkvw, qkvb, ln1w, ln1b, projw, fc1w, fc2w, rpi, rpb,
        q16, kvp16, wpack, biasPf);
    attn_kernel<<<NWIN * NHEADS * 4 * 2, 256, 0, stream>>>(q16, kvp16, biasPf, aop, lbuf);
    mlp_kernel<<<LTOK / 64, 512, 0, stream>>>(aop, aop + AOSTR, lbuf, wpack, projb, x,
                                              ln2w, ln2b, fc1b, fc2b, outp);
}